// Round 3
// baseline (500.593 us; speedup 1.0000x reference)
//
#include <hip/hip_runtime.h>

#define IN_F 32
#define OUT_F 32
#define EDGE_F 16
#define BN_EPS 1e-5f
#define SLOPE 0.01f

typedef _Float16 half_t;
typedef __attribute__((ext_vector_type(4))) _Float16 h4;
typedef __attribute__((ext_vector_type(8))) _Float16 h8;

// ---------------- K1: h0[n,:] = x[n,:] @ root + bias  -> agg (= d_out) ----------------
__global__ __launch_bounds__(256) void node_root_kernel(
    const float* __restrict__ x, const float* __restrict__ root,
    const float* __restrict__ bias, float* __restrict__ agg, int N) {
  __shared__ float rl[IN_F * OUT_F];
  __shared__ float bl[OUT_F];
  for (int t = threadIdx.x; t < IN_F * OUT_F; t += blockDim.x) rl[t] = root[t];
  if (threadIdx.x < OUT_F) bl[threadIdx.x] = bias[threadIdx.x];
  __syncthreads();

  int n = blockIdx.x * blockDim.x + threadIdx.x;
  bool valid = (n < N);
  int nu = valid ? n : 0;

  float xr[IN_F];
  const float4* xp = (const float4*)(x + (size_t)nu * IN_F);
#pragma unroll
  for (int q = 0; q < IN_F / 4; ++q) {
    float4 v = xp[q];
    xr[q * 4 + 0] = v.x; xr[q * 4 + 1] = v.y; xr[q * 4 + 2] = v.z; xr[q * 4 + 3] = v.w;
  }

  float acc[OUT_F];
#pragma unroll
  for (int o = 0; o < OUT_F; ++o) acc[o] = bl[o];
#pragma unroll
  for (int i = 0; i < IN_F; ++i) {
    float xi = xr[i];
#pragma unroll
    for (int o = 0; o < OUT_F; ++o) acc[o] = fmaf(xi, rl[i * OUT_F + o], acc[o]);
  }

  if (valid) {
    float4* op = (float4*)(agg + (size_t)n * OUT_F);
#pragma unroll
    for (int q = 0; q < OUT_F / 4; ++q)
      op[q] = make_float4(acc[q * 4 + 0], acc[q * 4 + 1], acc[q * 4 + 2], acc[q * 4 + 3]);
  }
}

// ---------------- K0: Y[n, f, o] = sum_i x[n,i] * W[f,i,o]  (fp16 out; f=16 slice = b) ----------------
// Y layout: [N][17][32] halves, row = 1088 B. Channel 16 = x @ b.
__global__ __launch_bounds__(256) void gemm_y_kernel(
    const float* __restrict__ x, const float* __restrict__ W,
    const float* __restrict__ b, half_t* __restrict__ Y, int N) {
  __shared__ float xl[32][33];
  __shared__ float Wl[4 * 32 * 32];  // 16 KB

  int f0 = blockIdx.y * 4;
  int n0 = blockIdx.x * 32;
  int tid = threadIdx.x;

  {
    int r = tid >> 3, p = tid & 7;
    int n = n0 + r;
    float4 v = make_float4(0.f, 0.f, 0.f, 0.f);
    if (n < N) v = *(const float4*)(x + (size_t)n * IN_F + p * 4);
    xl[r][p * 4 + 0] = v.x; xl[r][p * 4 + 1] = v.y;
    xl[r][p * 4 + 2] = v.z; xl[r][p * 4 + 3] = v.w;
  }
  {
    float4* Wl4 = (float4*)Wl;
#pragma unroll
    for (int k = 0; k < 4; ++k) {
      int idx = k * 256 + tid;
      int fi = idx >> 8;
      int rest = idx & 255;
      int f = f0 + fi;
      float4 v = make_float4(0.f, 0.f, 0.f, 0.f);
      if (f < 16)       v = *(const float4*)(W + (size_t)f * 1024 + rest * 4);
      else if (f == 16) v = *(const float4*)(b + rest * 4);
      Wl4[idx] = v;
    }
  }
  __syncthreads();

  int nl = tid >> 3, oq = tid & 7;
  int n = n0 + nl;
  const float4* Wl4 = (const float4*)Wl;
#pragma unroll
  for (int fi = 0; fi < 4; ++fi) {
    int f = f0 + fi;
    float4 acc = make_float4(0.f, 0.f, 0.f, 0.f);
#pragma unroll
    for (int i = 0; i < IN_F; ++i) {
      float xi = xl[nl][i];
      float4 w = Wl4[(fi * 32 + i) * 8 + oq];
      acc.x = fmaf(xi, w.x, acc.x);
      acc.y = fmaf(xi, w.y, acc.y);
      acc.z = fmaf(xi, w.z, acc.z);
      acc.w = fmaf(xi, w.w, acc.w);
    }
    if (n < N && f < 17) {
      h4 hv;
      hv[0] = (half_t)acc.x; hv[1] = (half_t)acc.y;
      hv[2] = (half_t)acc.z; hv[3] = (half_t)acc.w;
      *(h4*)(Y + (size_t)n * 544 + f * 32 + oq * 4) = hv;
    }
  }
}

// ---------------- K2: light edge kernel, 4 threads/edge, fp16 Y gather ----------------
__global__ __launch_bounds__(256) void edge_light_kernel(
    const half_t* __restrict__ Y, const float* __restrict__ ef,
    const int* __restrict__ ei, float* __restrict__ agg, int E) {
  int g = blockIdx.x * 256 + threadIdx.x;
  if (g >= E * 4) return;
  int e = g >> 2, oq = g & 3;  // oq: 8 consecutive outputs
  int s = ei[e];
  int d = ei[E + e];

  float efr[EDGE_F];
  const float4* ep = (const float4*)(ef + (size_t)e * EDGE_F);
#pragma unroll
  for (int q = 0; q < EDGE_F / 4; ++q) {
    float4 v = ep[q];
    efr[q * 4 + 0] = v.x; efr[q * 4 + 1] = v.y;
    efr[q * 4 + 2] = v.z; efr[q * 4 + 3] = v.w;
  }

  const half_t* yrow = Y + (size_t)s * 544 + oq * 8;

  float acc[8];
  {
    h8 v = *(const h8*)(yrow + 16 * 32);  // xb channel
#pragma unroll
    for (int j = 0; j < 8; ++j) acc[j] = (float)v[j];
  }
#pragma unroll
  for (int f = 0; f < EDGE_F; ++f) {
    h8 v = *(const h8*)(yrow + f * 32);
    float m = efr[f];
#pragma unroll
    for (int j = 0; j < 8; ++j) acc[j] = fmaf(m, (float)v[j], acc[j]);
  }

  float* dp = agg + (size_t)d * OUT_F + oq * 8;
#pragma unroll
  for (int j = 0; j < 8; ++j) atomicAdd(dp + j, acc[j]);
}

// ---------------- Fallback (round-1) edge kernel: W staged in LDS ----------------
__global__ __launch_bounds__(256) void edge_kernel(
    const float* __restrict__ x, const float* __restrict__ ef,
    const float* __restrict__ W, const float* __restrict__ b,
    const int* __restrict__ ei, float* __restrict__ agg, int E) {
  __shared__ float Wl[EDGE_F * IN_F * OUT_F];

  int e = blockIdx.x * blockDim.x + threadIdx.x;
  bool valid = (e < E);
  int eu = valid ? e : 0;
  int s = ei[eu];
  int d = ei[E + eu];

  float efr[EDGE_F];
  {
    const float4* ep = (const float4*)(ef + (size_t)eu * EDGE_F);
#pragma unroll
    for (int q = 0; q < EDGE_F / 4; ++q) {
      float4 v = ep[q];
      efr[q * 4 + 0] = v.x; efr[q * 4 + 1] = v.y;
      efr[q * 4 + 2] = v.z; efr[q * 4 + 3] = v.w;
    }
  }

  const float* xrow = x + (size_t)s * IN_F;
  float acc[OUT_F];
#pragma unroll
  for (int o = 0; o < OUT_F; ++o) acc[o] = 0.f;

  for (int t = threadIdx.x; t < IN_F * OUT_F; t += 256) Wl[t] = b[t];
  __syncthreads();
  for (int i = 0; i < IN_F; ++i) {
    float xi = xrow[i];
    const float* br = &Wl[i * OUT_F];
#pragma unroll
    for (int o = 0; o < OUT_F; ++o) acc[o] = fmaf(xi, br[o], acc[o]);
  }
  __syncthreads();

  for (int t = threadIdx.x; t < EDGE_F * IN_F * OUT_F / 4; t += 256)
    ((float4*)Wl)[t] = ((const float4*)W)[t];
  __syncthreads();

  for (int i = 0; i < IN_F; ++i) {
    float xi = xrow[i];
#pragma unroll
    for (int f = 0; f < EDGE_F; ++f) {
      float m = efr[f] * xi;
      const float* wr = &Wl[(f * IN_F + i) * OUT_F];
#pragma unroll
      for (int o = 0; o < OUT_F; ++o) acc[o] = fmaf(m, wr[o], acc[o]);
    }
  }

  if (valid) {
    float* dp = agg + (size_t)d * OUT_F;
#pragma unroll
    for (int o = 0; o < OUT_F; ++o) atomicAdd(dp + o, acc[o]);
  }
}

// ---------------- K3: BN stats ----------------
__global__ __launch_bounds__(256) void bn_stats_kernel(
    const float* __restrict__ h, float* __restrict__ stats, int total) {
  int t = blockIdx.x * blockDim.x + threadIdx.x;
  int stride = gridDim.x * blockDim.x;
  float s = 0.f, s2 = 0.f;
  for (int idx = t; idx < total; idx += stride) {
    float v = h[idx];
    s += v;
    s2 = fmaf(v, v, s2);
  }
  __shared__ float ls[256], ls2[256];
  ls[threadIdx.x] = s;
  ls2[threadIdx.x] = s2;
  __syncthreads();
  if (threadIdx.x < 32) {
    float a = ls[threadIdx.x], a2 = ls2[threadIdx.x];
    for (int j = 32 + threadIdx.x; j < 256; j += 32) { a += ls[j]; a2 += ls2[j]; }
    atomicAdd(&stats[threadIdx.x], a);
    atomicAdd(&stats[32 + threadIdx.x], a2);
  }
}

// ---------------- K4: normalize + affine + LeakyReLU ----------------
__global__ __launch_bounds__(256) void bn_apply_kernel(
    float* __restrict__ h, const float* __restrict__ stats,
    const float* __restrict__ gamma, const float* __restrict__ beta,
    int total, float invN) {
  int t = blockIdx.x * blockDim.x + threadIdx.x;
  int i4 = t * 4;
  if (i4 >= total) return;
  float4 v = *(const float4*)(h + i4);
  float r[4] = {v.x, v.y, v.z, v.w};
  int o0 = i4 & 31;
#pragma unroll
  for (int j = 0; j < 4; ++j) {
    int o = o0 + j;
    float m = stats[o] * invN;
    float var = fmaf(-m, m, stats[32 + o] * invN);
    float sc = rsqrtf(var + BN_EPS) * gamma[o];
    float val = (r[j] - m) * sc + beta[o];
    r[j] = val >= 0.f ? val : SLOPE * val;
  }
  *(float4*)(h + i4) = make_float4(r[0], r[1], r[2], r[3]);
}

extern "C" void kernel_launch(void* const* d_in, const int* in_sizes, int n_in,
                              void* d_out, int out_size, void* d_ws, size_t ws_size,
                              hipStream_t stream) {
  const float* x     = (const float*)d_in[0];
  const float* ef    = (const float*)d_in[1];
  const float* W     = (const float*)d_in[2];
  const float* b     = (const float*)d_in[3];
  const float* root  = (const float*)d_in[4];
  const float* bias  = (const float*)d_in[5];
  const float* gamma = (const float*)d_in[6];
  const float* beta  = (const float*)d_in[7];
  const int*   ei    = (const int*)d_in[8];

  float* out = (float*)d_out;
  float* stats = (float*)d_ws;                         // 64 floats
  half_t* Y = (half_t*)((char*)d_ws + 1024);           // [N][17][32] fp16

  int N = in_sizes[0] / IN_F;
  int E = in_sizes[1] / EDGE_F;
  int total = N * OUT_F;
  size_t need = 1024 + (size_t)N * 544 * sizeof(half_t);

  hipMemsetAsync(stats, 0, 64 * sizeof(float), stream);

  if (ws_size >= need) {
    gemm_y_kernel<<<dim3((N + 31) / 32, 5), 256, 0, stream>>>(x, W, b, Y, N);
    node_root_kernel<<<(N + 255) / 256, 256, 0, stream>>>(x, root, bias, out, N);
    edge_light_kernel<<<(E * 4 + 255) / 256, 256, 0, stream>>>(Y, ef, ei, out, E);
  } else {
    node_root_kernel<<<(N + 255) / 256, 256, 0, stream>>>(x, root, bias, out, N);
    edge_kernel<<<(E + 255) / 256, 256, 0, stream>>>(x, ef, W, b, ei, out, E);
  }
  bn_stats_kernel<<<1024, 256, 0, stream>>>(out, stats, total);
  bn_apply_kernel<<<(total / 4 + 255) / 256, 256, 0, stream>>>(out, stats, gamma, beta, total, 1.0f / (float)N);
}

// Round 4
// 215.448 us; speedup vs baseline: 2.3235x; 2.3235x over previous
//
#include <hip/hip_runtime.h>

#define IN_F 32
#define OUT_F 32
#define EDGE_F 16
#define BN_EPS 1e-5f
#define SLOPE 0.01f

typedef _Float16 half_t;
typedef __attribute__((ext_vector_type(4))) _Float16 h4;

// ---------------- K0: fused GEMM ----------------
// y<4 : Y[n, 4y+fi, o] = sum_i x[n,i]*W[4y+fi, i, o]        (fp16, Y row = [17][32])
// y==4: Y[n,16,o] = x@b ; out[n,o] = x@root + bias          (f32 h0 into d_out)
__global__ __launch_bounds__(256) void gemm_y_kernel(
    const float* __restrict__ x, const float* __restrict__ W,
    const float* __restrict__ b, const float* __restrict__ root,
    const float* __restrict__ bias, half_t* __restrict__ Y,
    float* __restrict__ out, int N) {
  __shared__ float xl[32][33];
  __shared__ float Wl[4 * 32 * 32];  // 16 KB: 4 slices of [32i][32o]

  bool last = (blockIdx.y == 4);
  int f0 = blockIdx.y * 4;
  int n0 = blockIdx.x * 32;
  int tid = threadIdx.x;

  {  // stage x tile [32 nodes][32 feats]
    int r = tid >> 3, p = tid & 7;
    int n = n0 + r;
    float4 v = make_float4(0.f, 0.f, 0.f, 0.f);
    if (n < N) v = *(const float4*)(x + (size_t)n * IN_F + p * 4);
    xl[r][p * 4 + 0] = v.x; xl[r][p * 4 + 1] = v.y;
    xl[r][p * 4 + 2] = v.z; xl[r][p * 4 + 3] = v.w;
  }
  {  // stage 4 weight slices
    float4* Wl4 = (float4*)Wl;
#pragma unroll
    for (int k = 0; k < 4; ++k) {
      int idx = k * 256 + tid;
      int fi = idx >> 8;
      int rest = idx & 255;
      float4 v = make_float4(0.f, 0.f, 0.f, 0.f);
      if (!last)          v = *(const float4*)(W + (size_t)(f0 + fi) * 1024 + rest * 4);
      else if (fi == 0)   v = *(const float4*)(b + rest * 4);
      else if (fi == 1)   v = *(const float4*)(root + rest * 4);
      Wl4[idx] = v;
    }
  }
  __syncthreads();

  int nl = tid >> 3, oq = tid & 7;
  int n = n0 + nl;
  const float4* Wl4 = (const float4*)Wl;
  int nfi = last ? 2 : 4;
  for (int fi = 0; fi < nfi; ++fi) {
    float4 acc = make_float4(0.f, 0.f, 0.f, 0.f);
#pragma unroll
    for (int i = 0; i < IN_F; ++i) {
      float xi = xl[nl][i];
      float4 w = Wl4[(fi * 32 + i) * 8 + oq];
      acc.x = fmaf(xi, w.x, acc.x);
      acc.y = fmaf(xi, w.y, acc.y);
      acc.z = fmaf(xi, w.z, acc.z);
      acc.w = fmaf(xi, w.w, acc.w);
    }
    if (n < N) {
      if (!last || fi == 0) {
        h4 hv;
        hv[0] = (half_t)acc.x; hv[1] = (half_t)acc.y;
        hv[2] = (half_t)acc.z; hv[3] = (half_t)acc.w;
        *(h4*)(Y + (size_t)n * 544 + (f0 + fi) * 32 + oq * 4) = hv;
      } else {  // root + bias -> h0
        float4 bv = *(const float4*)(bias + oq * 4);
        acc.x += bv.x; acc.y += bv.y; acc.z += bv.z; acc.w += bv.w;
        *(float4*)(out + (size_t)n * OUT_F + oq * 4) = acc;
      }
    }
  }
}

// ---------------- K2: edge kernel, 8 lanes/edge, sector-coalesced atomics ----------------
__global__ __launch_bounds__(256) void edge_light_kernel(
    const half_t* __restrict__ Y, const float* __restrict__ ef,
    const int* __restrict__ ei, float* __restrict__ agg, int E) {
  __shared__ float efl[32][17];   // ef rows for 32 edges (pad 17: conflict-free)
  __shared__ float msg[32][33];   // per-edge 32-float messages (pad 33)
  __shared__ int dstl[32];

  int e0 = blockIdx.x * 32;
  int t = threadIdx.x;
  int el = t >> 3, oq = t & 7;
  int e = e0 + el;
  bool ev = (e < E);

  // stage ef: 32 edges x 16 floats = 128 float4
  if (t < 128) {
    int ee = e0 + (t >> 2);
    int q = t & 3;
    float4 v = make_float4(0.f, 0.f, 0.f, 0.f);
    if (ee < E) v = *(const float4*)(ef + (size_t)ee * EDGE_F + q * 4);
    efl[t >> 2][q * 4 + 0] = v.x; efl[t >> 2][q * 4 + 1] = v.y;
    efl[t >> 2][q * 4 + 2] = v.z; efl[t >> 2][q * 4 + 3] = v.w;
  }
  if (t < 32) {
    int ee = e0 + t;
    dstl[t] = (ee < E) ? ei[E + ee] : -1;
  }
  int s = ev ? ei[e] : 0;
  __syncthreads();

  // gather + per-edge matvec: lane oq owns outputs 4oq..4oq+3
  const half_t* yrow = Y + (size_t)s * 544 + oq * 4;
  float acc[4];
  {
    h4 v = *(const h4*)(yrow + 16 * 32);  // xb channel
#pragma unroll
    for (int j = 0; j < 4; ++j) acc[j] = (float)v[j];
  }
#pragma unroll
  for (int f = 0; f < EDGE_F; ++f) {
    float m = efl[el][f];
    h4 v = *(const h4*)(yrow + f * 32);
#pragma unroll
    for (int j = 0; j < 4; ++j) acc[j] = fmaf(m, (float)v[j], acc[j]);
  }
#pragma unroll
  for (int j = 0; j < 4; ++j) msg[el][oq * 4 + j] = acc[j];
  __syncthreads();

  // atomic phase: instr j writes 8 consecutive floats per edge = 1 sector
  int d = dstl[el];
  if (d >= 0) {
    float* dp = agg + (size_t)d * OUT_F;
#pragma unroll
    for (int j = 0; j < 4; ++j)
      atomicAdd(dp + j * 8 + oq, msg[el][j * 8 + oq]);
  }
}

// ---------------- Fallback path (small ws): round-1 kernels ----------------
__global__ __launch_bounds__(256) void node_root_kernel(
    const float* __restrict__ x, const float* __restrict__ root,
    const float* __restrict__ bias, float* __restrict__ agg, int N) {
  __shared__ float rl[IN_F * OUT_F];
  __shared__ float bl[OUT_F];
  for (int t = threadIdx.x; t < IN_F * OUT_F; t += blockDim.x) rl[t] = root[t];
  if (threadIdx.x < OUT_F) bl[threadIdx.x] = bias[threadIdx.x];
  __syncthreads();
  int n = blockIdx.x * blockDim.x + threadIdx.x;
  bool valid = (n < N);
  int nu = valid ? n : 0;
  float xr[IN_F];
  const float4* xp = (const float4*)(x + (size_t)nu * IN_F);
#pragma unroll
  for (int q = 0; q < IN_F / 4; ++q) {
    float4 v = xp[q];
    xr[q * 4 + 0] = v.x; xr[q * 4 + 1] = v.y; xr[q * 4 + 2] = v.z; xr[q * 4 + 3] = v.w;
  }
  float acc[OUT_F];
#pragma unroll
  for (int o = 0; o < OUT_F; ++o) acc[o] = bl[o];
#pragma unroll
  for (int i = 0; i < IN_F; ++i) {
    float xi = xr[i];
#pragma unroll
    for (int o = 0; o < OUT_F; ++o) acc[o] = fmaf(xi, rl[i * OUT_F + o], acc[o]);
  }
  if (valid) {
    float4* op = (float4*)(agg + (size_t)n * OUT_F);
#pragma unroll
    for (int q = 0; q < OUT_F / 4; ++q)
      op[q] = make_float4(acc[q * 4 + 0], acc[q * 4 + 1], acc[q * 4 + 2], acc[q * 4 + 3]);
  }
}

__global__ __launch_bounds__(256) void edge_kernel(
    const float* __restrict__ x, const float* __restrict__ ef,
    const float* __restrict__ W, const float* __restrict__ b,
    const int* __restrict__ ei, float* __restrict__ agg, int E) {
  __shared__ float Wl[EDGE_F * IN_F * OUT_F];
  int e = blockIdx.x * blockDim.x + threadIdx.x;
  bool valid = (e < E);
  int eu = valid ? e : 0;
  int s = ei[eu];
  int d = ei[E + eu];
  float efr[EDGE_F];
  {
    const float4* ep = (const float4*)(ef + (size_t)eu * EDGE_F);
#pragma unroll
    for (int q = 0; q < EDGE_F / 4; ++q) {
      float4 v = ep[q];
      efr[q * 4 + 0] = v.x; efr[q * 4 + 1] = v.y;
      efr[q * 4 + 2] = v.z; efr[q * 4 + 3] = v.w;
    }
  }
  const float* xrow = x + (size_t)s * IN_F;
  float acc[OUT_F];
#pragma unroll
  for (int o = 0; o < OUT_F; ++o) acc[o] = 0.f;
  for (int t = threadIdx.x; t < IN_F * OUT_F; t += 256) Wl[t] = b[t];
  __syncthreads();
  for (int i = 0; i < IN_F; ++i) {
    float xi = xrow[i];
    const float* br = &Wl[i * OUT_F];
#pragma unroll
    for (int o = 0; o < OUT_F; ++o) acc[o] = fmaf(xi, br[o], acc[o]);
  }
  __syncthreads();
  for (int t = threadIdx.x; t < EDGE_F * IN_F * OUT_F / 4; t += 256)
    ((float4*)Wl)[t] = ((const float4*)W)[t];
  __syncthreads();
  for (int i = 0; i < IN_F; ++i) {
    float xi = xrow[i];
#pragma unroll
    for (int f = 0; f < EDGE_F; ++f) {
      float m = efr[f] * xi;
      const float* wr = &Wl[(f * IN_F + i) * OUT_F];
#pragma unroll
      for (int o = 0; o < OUT_F; ++o) acc[o] = fmaf(m, wr[o], acc[o]);
    }
  }
  if (valid) {
    float* dp = agg + (size_t)d * OUT_F;
#pragma unroll
    for (int o = 0; o < OUT_F; ++o) atomicAdd(dp + o, acc[o]);
  }
}

// ---------------- K3: BN stats ----------------
__global__ __launch_bounds__(256) void bn_stats_kernel(
    const float* __restrict__ h, float* __restrict__ stats, int total) {
  int t = blockIdx.x * blockDim.x + threadIdx.x;
  int stride = gridDim.x * blockDim.x;
  float s = 0.f, s2 = 0.f;
  for (int idx = t; idx < total; idx += stride) {
    float v = h[idx];
    s += v;
    s2 = fmaf(v, v, s2);
  }
  __shared__ float ls[256], ls2[256];
  ls[threadIdx.x] = s;
  ls2[threadIdx.x] = s2;
  __syncthreads();
  if (threadIdx.x < 32) {
    float a = ls[threadIdx.x], a2 = ls2[threadIdx.x];
    for (int j = 32 + threadIdx.x; j < 256; j += 32) { a += ls[j]; a2 += ls2[j]; }
    atomicAdd(&stats[threadIdx.x], a);
    atomicAdd(&stats[32 + threadIdx.x], a2);
  }
}

// ---------------- K4: normalize + affine + LeakyReLU ----------------
__global__ __launch_bounds__(256) void bn_apply_kernel(
    float* __restrict__ h, const float* __restrict__ stats,
    const float* __restrict__ gamma, const float* __restrict__ beta,
    int total, float invN) {
  int t = blockIdx.x * blockDim.x + threadIdx.x;
  int i4 = t * 4;
  if (i4 >= total) return;
  float4 v = *(const float4*)(h + i4);
  float r[4] = {v.x, v.y, v.z, v.w};
  int o0 = i4 & 31;
#pragma unroll
  for (int j = 0; j < 4; ++j) {
    int o = o0 + j;
    float m = stats[o] * invN;
    float var = fmaf(-m, m, stats[32 + o] * invN);
    float sc = rsqrtf(var + BN_EPS) * gamma[o];
    float val = (r[j] - m) * sc + beta[o];
    r[j] = val >= 0.f ? val : SLOPE * val;
  }
  *(float4*)(h + i4) = make_float4(r[0], r[1], r[2], r[3]);
}

extern "C" void kernel_launch(void* const* d_in, const int* in_sizes, int n_in,
                              void* d_out, int out_size, void* d_ws, size_t ws_size,
                              hipStream_t stream) {
  const float* x     = (const float*)d_in[0];
  const float* ef    = (const float*)d_in[1];
  const float* W     = (const float*)d_in[2];
  const float* b     = (const float*)d_in[3];
  const float* root  = (const float*)d_in[4];
  const float* bias  = (const float*)d_in[5];
  const float* gamma = (const float*)d_in[6];
  const float* beta  = (const float*)d_in[7];
  const int*   ei    = (const int*)d_in[8];

  float* out = (float*)d_out;
  float* stats = (float*)d_ws;                 // 64 floats
  half_t* Y = (half_t*)((char*)d_ws + 1024);   // [N][17][32] fp16

  int N = in_sizes[0] / IN_F;
  int E = in_sizes[1] / EDGE_F;
  int total = N * OUT_F;
  size_t need = 1024 + (size_t)N * 544 * sizeof(half_t);

  hipMemsetAsync(stats, 0, 64 * sizeof(float), stream);

  if (ws_size >= need) {
    gemm_y_kernel<<<dim3((N + 31) / 32, 5), 256, 0, stream>>>(x, W, b, root, bias, Y, out, N);
    edge_light_kernel<<<(E + 31) / 32, 256, 0, stream>>>(Y, ef, ei, out, E);
  } else {
    node_root_kernel<<<(N + 255) / 256, 256, 0, stream>>>(x, root, bias, out, N);
    edge_kernel<<<(E + 255) / 256, 256, 0, stream>>>(x, ef, W, b, ei, out, E);
  }
  bn_stats_kernel<<<1024, 256, 0, stream>>>(out, stats, total);
  bn_apply_kernel<<<(total / 4 + 255) / 256, 256, 0, stream>>>(out, stats, gamma, beta, total, 1.0f / (float)N);
}

// Round 5
// 190.177 us; speedup vs baseline: 2.6322x; 1.1329x over previous
//
#include <hip/hip_runtime.h>

#define IN_F 32
#define OUT_F 32
#define EDGE_F 16
#define BN_EPS 1e-5f
#define SLOPE 0.01f

typedef _Float16 half_t;
typedef __attribute__((ext_vector_type(4))) _Float16 h4;
typedef __attribute__((ext_vector_type(8))) _Float16 f16x8;
typedef __attribute__((ext_vector_type(4))) float f32x4;

// B matrix geometry: 576 cols = [W: f*32+o for f<16 | xb: 512+o | root: 544+o], K=32.
#define BCOLS 576
#define BSTRIDE_B 80  // bytes per col in LDS (64 data + 16 pad): 16B-aligned, 2-way max conflict

// ---------------- P0: build Bt[col][k] fp16 (col-major B) in ws ----------------
__global__ __launch_bounds__(256) void prep_bt_kernel(
    const float* __restrict__ W, const float* __restrict__ b,
    const float* __restrict__ root, half_t* __restrict__ BtG) {
  for (int idx = threadIdx.x; idx < BCOLS * 32; idx += 256) {
    int col = idx >> 5, k = idx & 31;
    float v;
    if (col < 512) {
      int f = col >> 5, o = col & 31;
      v = W[(size_t)f * 1024 + k * 32 + o];
    } else if (col < 544) {
      v = b[k * 32 + (col - 512)];
    } else {
      v = root[k * 32 + (col - 544)];
    }
    BtG[(size_t)col * 32 + k] = (half_t)v;
  }
}

// ---------------- K0: MFMA GEMM: [N x 32] @ [32 x 576] ----------------
// cols <544 -> Y fp16 ([N][17][32]); cols 544..575 -> +bias -> out f32 (h0)
__global__ __launch_bounds__(256) void gemm_y_mfma_kernel(
    const float* __restrict__ x, const half_t* __restrict__ BtG,
    const float* __restrict__ bias, half_t* __restrict__ Y,
    float* __restrict__ out, int N) {
  __shared__ char BtL[BCOLS * BSTRIDE_B];  // 46080 B

  int tid = threadIdx.x;
  // stage Bt: 576 cols x 64B -> 80B slots
  for (int t = tid; t < BCOLS * 4; t += 256) {
    int col = t >> 2, part = t & 3;
    *(float4*)(BtL + col * BSTRIDE_B + part * 16) =
        *(const float4*)((const char*)BtG + col * 64 + part * 16);
  }
  __syncthreads();

  int wv = tid >> 6, lane = tid & 63;
  int lr = lane & 15, kg = lane >> 4;  // row/col-within-tile, k-group
  int n0 = blockIdx.x * 64 + wv * 16;
  int row = n0 + lr;

  // A fragment: x[row][kg*8 .. +7] as fp16 (k-permutation cancels between A and B)
  f16x8 a;
  if (row < N) {
    float4 u0 = *(const float4*)(x + (size_t)row * 32 + kg * 8);
    float4 u1 = *(const float4*)(x + (size_t)row * 32 + kg * 8 + 4);
    a[0] = (half_t)u0.x; a[1] = (half_t)u0.y; a[2] = (half_t)u0.z; a[3] = (half_t)u0.w;
    a[4] = (half_t)u1.x; a[5] = (half_t)u1.y; a[6] = (half_t)u1.z; a[7] = (half_t)u1.w;
  } else {
    a = (f16x8)(half_t)0.f;
  }

  for (int ct = 0; ct < 36; ++ct) {
    int col = ct * 16 + lr;
    f16x8 bf = *(const f16x8*)(BtL + col * BSTRIDE_B + kg * 16);
    f32x4 c = {0.f, 0.f, 0.f, 0.f};
    c = __builtin_amdgcn_mfma_f32_16x16x32_f16(a, bf, c, 0, 0, 0);
    // C/D: col = lane&15, row = (lane>>4)*4 + j   [m89-verified, dtype-independent]
    if (col < 544) {
#pragma unroll
      for (int j = 0; j < 4; ++j) {
        int n = n0 + kg * 4 + j;
        if (n < N) Y[(size_t)n * 544 + col] = (half_t)c[j];
      }
    } else {
      int o = col - 544;
      float bv = bias[o];
#pragma unroll
      for (int j = 0; j < 4; ++j) {
        int n = n0 + kg * 4 + j;
        if (n < N) out[(size_t)n * OUT_F + o] = c[j] + bv;
      }
    }
  }
}

// ---------------- K2: edge kernel, 8 lanes/edge, hoisted gather, sector atomics ----------------
__global__ __launch_bounds__(256) void edge_light_kernel(
    const half_t* __restrict__ Y, const float* __restrict__ ef,
    const int* __restrict__ ei, float* __restrict__ agg, int E) {
  __shared__ float efl[32][17];
  __shared__ float msg[32][33];
  __shared__ int dstl[32];

  int e0 = blockIdx.x * 32;
  int t = threadIdx.x;
  int el = t >> 3, oq = t & 7;
  int e = e0 + el;
  bool ev = (e < E);
  int s = ev ? ei[e] : 0;

  if (t < 128) {
    int ee = e0 + (t >> 2);
    int q = t & 3;
    float4 v = make_float4(0.f, 0.f, 0.f, 0.f);
    if (ee < E) v = *(const float4*)(ef + (size_t)ee * EDGE_F + q * 4);
    efl[t >> 2][q * 4 + 0] = v.x; efl[t >> 2][q * 4 + 1] = v.y;
    efl[t >> 2][q * 4 + 2] = v.z; efl[t >> 2][q * 4 + 3] = v.w;
  }
  if (t < 32) {
    int ee = e0 + t;
    dstl[t] = (ee < E) ? ei[E + ee] : -1;
  }

  // hoisted gather: all 17 h4 loads in flight before use
  const half_t* yrow = Y + (size_t)s * 544 + oq * 4;
  h4 yv[17];
#pragma unroll
  for (int f = 0; f < 17; ++f) yv[f] = *(const h4*)(yrow + f * 32);

  __syncthreads();

  float acc[4];
#pragma unroll
  for (int j = 0; j < 4; ++j) acc[j] = (float)yv[16][j];
#pragma unroll
  for (int f = 0; f < EDGE_F; ++f) {
    float m = efl[el][f];
#pragma unroll
    for (int j = 0; j < 4; ++j) acc[j] = fmaf(m, (float)yv[f][j], acc[j]);
  }
#pragma unroll
  for (int j = 0; j < 4; ++j) msg[el][oq * 4 + j] = acc[j];
  __syncthreads();

  int d = dstl[el];
  if (d >= 0) {
    float* dp = agg + (size_t)d * OUT_F;
#pragma unroll
    for (int j = 0; j < 4; ++j)
      atomicAdd(dp + j * 8 + oq, msg[el][j * 8 + oq]);
  }
}

// ---------------- Fallback path (small ws) ----------------
__global__ __launch_bounds__(256) void node_root_kernel(
    const float* __restrict__ x, const float* __restrict__ root,
    const float* __restrict__ bias, float* __restrict__ agg, int N) {
  __shared__ float rl[IN_F * OUT_F];
  __shared__ float bl[OUT_F];
  for (int t = threadIdx.x; t < IN_F * OUT_F; t += blockDim.x) rl[t] = root[t];
  if (threadIdx.x < OUT_F) bl[threadIdx.x] = bias[threadIdx.x];
  __syncthreads();
  int n = blockIdx.x * blockDim.x + threadIdx.x;
  bool valid = (n < N);
  int nu = valid ? n : 0;
  float xr[IN_F];
  const float4* xp = (const float4*)(x + (size_t)nu * IN_F);
#pragma unroll
  for (int q = 0; q < IN_F / 4; ++q) {
    float4 v = xp[q];
    xr[q * 4 + 0] = v.x; xr[q * 4 + 1] = v.y; xr[q * 4 + 2] = v.z; xr[q * 4 + 3] = v.w;
  }
  float acc[OUT_F];
#pragma unroll
  for (int o = 0; o < OUT_F; ++o) acc[o] = bl[o];
#pragma unroll
  for (int i = 0; i < IN_F; ++i) {
    float xi = xr[i];
#pragma unroll
    for (int o = 0; o < OUT_F; ++o) acc[o] = fmaf(xi, rl[i * OUT_F + o], acc[o]);
  }
  if (valid) {
    float4* op = (float4*)(agg + (size_t)n * OUT_F);
#pragma unroll
    for (int q = 0; q < OUT_F / 4; ++q)
      op[q] = make_float4(acc[q * 4 + 0], acc[q * 4 + 1], acc[q * 4 + 2], acc[q * 4 + 3]);
  }
}

__global__ __launch_bounds__(256) void edge_kernel(
    const float* __restrict__ x, const float* __restrict__ ef,
    const float* __restrict__ W, const float* __restrict__ b,
    const int* __restrict__ ei, float* __restrict__ agg, int E) {
  __shared__ float Wl[EDGE_F * IN_F * OUT_F];
  int e = blockIdx.x * blockDim.x + threadIdx.x;
  bool valid = (e < E);
  int eu = valid ? e : 0;
  int s = ei[eu];
  int d = ei[E + eu];
  float efr[EDGE_F];
  {
    const float4* ep = (const float4*)(ef + (size_t)eu * EDGE_F);
#pragma unroll
    for (int q = 0; q < EDGE_F / 4; ++q) {
      float4 v = ep[q];
      efr[q * 4 + 0] = v.x; efr[q * 4 + 1] = v.y;
      efr[q * 4 + 2] = v.z; efr[q * 4 + 3] = v.w;
    }
  }
  const float* xrow = x + (size_t)s * IN_F;
  float acc[OUT_F];
#pragma unroll
  for (int o = 0; o < OUT_F; ++o) acc[o] = 0.f;
  for (int t = threadIdx.x; t < IN_F * OUT_F; t += 256) Wl[t] = b[t];
  __syncthreads();
  for (int i = 0; i < IN_F; ++i) {
    float xi = xrow[i];
    const float* br = &Wl[i * OUT_F];
#pragma unroll
    for (int o = 0; o < OUT_F; ++o) acc[o] = fmaf(xi, br[o], acc[o]);
  }
  __syncthreads();
  for (int t = threadIdx.x; t < EDGE_F * IN_F * OUT_F / 4; t += 256)
    ((float4*)Wl)[t] = ((const float4*)W)[t];
  __syncthreads();
  for (int i = 0; i < IN_F; ++i) {
    float xi = xrow[i];
#pragma unroll
    for (int f = 0; f < EDGE_F; ++f) {
      float m = efr[f] * xi;
      const float* wr = &Wl[(f * IN_F + i) * OUT_F];
#pragma unroll
      for (int o = 0; o < OUT_F; ++o) acc[o] = fmaf(m, wr[o], acc[o]);
    }
  }
  if (valid) {
    float* dp = agg + (size_t)d * OUT_F;
#pragma unroll
    for (int o = 0; o < OUT_F; ++o) atomicAdd(dp + o, acc[o]);
  }
}

// ---------------- K3: BN stats ----------------
__global__ __launch_bounds__(256) void bn_stats_kernel(
    const float* __restrict__ h, float* __restrict__ stats, int total) {
  int t = blockIdx.x * blockDim.x + threadIdx.x;
  int stride = gridDim.x * blockDim.x;
  float s = 0.f, s2 = 0.f;
  for (int idx = t; idx < total; idx += stride) {
    float v = h[idx];
    s += v;
    s2 = fmaf(v, v, s2);
  }
  __shared__ float ls[256], ls2[256];
  ls[threadIdx.x] = s;
  ls2[threadIdx.x] = s2;
  __syncthreads();
  if (threadIdx.x < 32) {
    float a = ls[threadIdx.x], a2 = ls2[threadIdx.x];
    for (int j = 32 + threadIdx.x; j < 256; j += 32) { a += ls[j]; a2 += ls2[j]; }
    atomicAdd(&stats[threadIdx.x], a);
    atomicAdd(&stats[32 + threadIdx.x], a2);
  }
}

// ---------------- K4: normalize + affine + LeakyReLU ----------------
__global__ __launch_bounds__(256) void bn_apply_kernel(
    float* __restrict__ h, const float* __restrict__ stats,
    const float* __restrict__ gamma, const float* __restrict__ beta,
    int total, float invN) {
  int t = blockIdx.x * blockDim.x + threadIdx.x;
  int i4 = t * 4;
  if (i4 >= total) return;
  float4 v = *(const float4*)(h + i4);
  float r[4] = {v.x, v.y, v.z, v.w};
  int o0 = i4 & 31;
#pragma unroll
  for (int j = 0; j < 4; ++j) {
    int o = o0 + j;
    float m = stats[o] * invN;
    float var = fmaf(-m, m, stats[32 + o] * invN);
    float sc = rsqrtf(var + BN_EPS) * gamma[o];
    float val = (r[j] - m) * sc + beta[o];
    r[j] = val >= 0.f ? val : SLOPE * val;
  }
  *(float4*)(h + i4) = make_float4(r[0], r[1], r[2], r[3]);
}

extern "C" void kernel_launch(void* const* d_in, const int* in_sizes, int n_in,
                              void* d_out, int out_size, void* d_ws, size_t ws_size,
                              hipStream_t stream) {
  const float* x     = (const float*)d_in[0];
  const float* ef    = (const float*)d_in[1];
  const float* W     = (const float*)d_in[2];
  const float* b     = (const float*)d_in[3];
  const float* root  = (const float*)d_in[4];
  const float* bias  = (const float*)d_in[5];
  const float* gamma = (const float*)d_in[6];
  const float* beta  = (const float*)d_in[7];
  const int*   ei    = (const int*)d_in[8];

  float* out = (float*)d_out;
  float* stats = (float*)d_ws;                        // 64 floats @ 0
  half_t* BtG = (half_t*)((char*)d_ws + 1024);        // 576*32 fp16 = 36864 B
  half_t* Y = (half_t*)((char*)d_ws + 1024 + 36864);  // [N][17][32] fp16

  int N = in_sizes[0] / IN_F;
  int E = in_sizes[1] / EDGE_F;
  int total = N * OUT_F;
  size_t need = 1024 + 36864 + (size_t)N * 544 * sizeof(half_t);

  hipMemsetAsync(stats, 0, 64 * sizeof(float), stream);

  if (ws_size >= need) {
    prep_bt_kernel<<<1, 256, 0, stream>>>(W, b, root, BtG);
    gemm_y_mfma_kernel<<<(N + 63) / 64, 256, 0, stream>>>(x, BtG, bias, Y, out, N);
    edge_light_kernel<<<(E + 31) / 32, 256, 0, stream>>>(Y, ef, ei, out, E);
  } else {
    node_root_kernel<<<(N + 255) / 256, 256, 0, stream>>>(x, root, bias, out, N);
    edge_kernel<<<(E + 255) / 256, 256, 0, stream>>>(x, ef, W, b, ei, out, E);
  }
  bn_stats_kernel<<<1024, 256, 0, stream>>>(out, stats, total);
  bn_apply_kernel<<<(total / 4 + 255) / 256, 256, 0, stream>>>(out, stats, gamma, beta, total, 1.0f / (float)N);
}

// Round 6
// 180.264 us; speedup vs baseline: 2.7770x; 1.0550x over previous
//
#include <hip/hip_runtime.h>

#define IN_F 32
#define OUT_F 32
#define EDGE_F 16
#define BN_EPS 1e-5f
#define SLOPE 0.01f

typedef _Float16 half_t;
typedef __attribute__((ext_vector_type(4))) _Float16 h4;
typedef __attribute__((ext_vector_type(8))) _Float16 f16x8;
typedef __attribute__((ext_vector_type(4))) float f32x4;

// B matrix geometry: 576 cols = [W: f*32+o for f<16 | xb: 512+o | root: 544+o], K=32.
#define BCOLS 576
#define BSTRIDE_B 80  // bytes per col in LDS (64 data + 16 pad): 16B-aligned, 2-way max conflict

// ---------------- P0: build Bt[col][k] fp16 (col-major B) in ws ----------------
// thread -> (k, o) with o contiguous => coalesced W reads; scattered 2B writes land in L2.
__global__ __launch_bounds__(256) void prep_bt_kernel(
    const float* __restrict__ W, const float* __restrict__ b,
    const float* __restrict__ root, half_t* __restrict__ BtG) {
  int idx = blockIdx.x * 256 + threadIdx.x;  // idx = row-major over [18 rows=f' ][32 k][32 o]
  if (idx >= BCOLS * 32) return;
  int o = idx & 31;
  int k = (idx >> 5) & 31;
  int fp = idx >> 10;  // 0..17
  float v;
  int col;
  if (fp < 16) {
    v = W[(size_t)fp * 1024 + k * 32 + o];
    col = fp * 32 + o;
  } else if (fp == 16) {
    v = b[k * 32 + o];
    col = 512 + o;
  } else {
    v = root[k * 32 + o];
    col = 544 + o;
  }
  BtG[(size_t)col * 32 + k] = (half_t)v;
}

// ---------------- K0: MFMA GEMM: [N x 32] @ [32 x 576] ----------------
// cols <544 -> Y fp16 ([N][17][32]); cols 544..575 -> +bias -> out f32 (h0)
__global__ __launch_bounds__(256) void gemm_y_mfma_kernel(
    const float* __restrict__ x, const half_t* __restrict__ BtG,
    const float* __restrict__ bias, half_t* __restrict__ Y,
    float* __restrict__ out, int N) {
  __shared__ char BtL[BCOLS * BSTRIDE_B];  // 46080 B

  int tid = threadIdx.x;
  for (int t = tid; t < BCOLS * 4; t += 256) {
    int col = t >> 2, part = t & 3;
    *(float4*)(BtL + col * BSTRIDE_B + part * 16) =
        *(const float4*)((const char*)BtG + col * 64 + part * 16);
  }
  __syncthreads();

  int wv = tid >> 6, lane = tid & 63;
  int lr = lane & 15, kg = lane >> 4;
  int n0 = blockIdx.x * 64 + wv * 16;
  int row = n0 + lr;

  f16x8 a;
  if (row < N) {
    float4 u0 = *(const float4*)(x + (size_t)row * 32 + kg * 8);
    float4 u1 = *(const float4*)(x + (size_t)row * 32 + kg * 8 + 4);
    a[0] = (half_t)u0.x; a[1] = (half_t)u0.y; a[2] = (half_t)u0.z; a[3] = (half_t)u0.w;
    a[4] = (half_t)u1.x; a[5] = (half_t)u1.y; a[6] = (half_t)u1.z; a[7] = (half_t)u1.w;
  } else {
    a = (f16x8)(half_t)0.f;
  }

  for (int ct = 0; ct < 36; ++ct) {
    int col = ct * 16 + lr;
    f16x8 bf = *(const f16x8*)(BtL + col * BSTRIDE_B + kg * 16);
    f32x4 c = {0.f, 0.f, 0.f, 0.f};
    c = __builtin_amdgcn_mfma_f32_16x16x32_f16(a, bf, c, 0, 0, 0);
    if (col < 544) {
#pragma unroll
      for (int j = 0; j < 4; ++j) {
        int n = n0 + kg * 4 + j;
        if (n < N) Y[(size_t)n * 544 + col] = (half_t)c[j];
      }
    } else {
      int o = col - 544;
      float bv = bias[o];
#pragma unroll
      for (int j = 0; j < 4; ++j) {
        int n = n0 + kg * 4 + j;
        if (n < N) out[(size_t)n * OUT_F + o] = c[j] + bv;
      }
    }
  }
}

// ---------------- K2: edge kernel, 8 lanes/edge, clustered gather, sector atomics ----------------
__global__ __launch_bounds__(256) void edge_light_kernel(
    const half_t* __restrict__ Y, const float* __restrict__ ef,
    const int* __restrict__ ei, float* __restrict__ agg, int E) {
  __shared__ float efl[32][17];
  __shared__ float msg[32][33];
  __shared__ int dstl[32];

  int e0 = blockIdx.x * 32;
  int t = threadIdx.x;
  int el = t >> 3, oq = t & 7;
  int e = e0 + el;
  bool ev = (e < E);
  int s = ev ? ei[e] : 0;

  // issue ALL 17 gather loads and keep them in flight (sched_barrier pins the cluster)
  const half_t* yrow = Y + (size_t)s * 544 + oq * 4;
  h4 yv[17];
#pragma unroll
  for (int f = 0; f < 17; ++f) yv[f] = *(const h4*)(yrow + f * 32);
  __builtin_amdgcn_sched_barrier(0);

  if (t < 128) {
    int ee = e0 + (t >> 2);
    int q = t & 3;
    float4 v = make_float4(0.f, 0.f, 0.f, 0.f);
    if (ee < E) v = *(const float4*)(ef + (size_t)ee * EDGE_F + q * 4);
    efl[t >> 2][q * 4 + 0] = v.x; efl[t >> 2][q * 4 + 1] = v.y;
    efl[t >> 2][q * 4 + 2] = v.z; efl[t >> 2][q * 4 + 3] = v.w;
  }
  if (t < 32) {
    int ee = e0 + t;
    dstl[t] = (ee < E) ? ei[E + ee] : -1;
  }
  __syncthreads();

  float acc[4];
#pragma unroll
  for (int j = 0; j < 4; ++j) acc[j] = (float)yv[16][j];
#pragma unroll
  for (int f = 0; f < EDGE_F; ++f) {
    float m = efl[el][f];
#pragma unroll
    for (int j = 0; j < 4; ++j) acc[j] = fmaf(m, (float)yv[f][j], acc[j]);
  }
#pragma unroll
  for (int j = 0; j < 4; ++j) msg[el][oq * 4 + j] = acc[j];
  __syncthreads();

  int d = dstl[el];
  if (d >= 0) {
    float* dp = agg + (size_t)d * OUT_F;
#pragma unroll
    for (int j = 0; j < 4; ++j)
      atomicAdd(dp + j * 8 + oq, msg[el][j * 8 + oq]);
  }
}

// ---------------- Fallback path (small ws) ----------------
__global__ __launch_bounds__(256) void node_root_kernel(
    const float* __restrict__ x, const float* __restrict__ root,
    const float* __restrict__ bias, float* __restrict__ agg, int N) {
  __shared__ float rl[IN_F * OUT_F];
  __shared__ float bl[OUT_F];
  for (int t = threadIdx.x; t < IN_F * OUT_F; t += blockDim.x) rl[t] = root[t];
  if (threadIdx.x < OUT_F) bl[threadIdx.x] = bias[threadIdx.x];
  __syncthreads();
  int n = blockIdx.x * blockDim.x + threadIdx.x;
  bool valid = (n < N);
  int nu = valid ? n : 0;
  float xr[IN_F];
  const float4* xp = (const float4*)(x + (size_t)nu * IN_F);
#pragma unroll
  for (int q = 0; q < IN_F / 4; ++q) {
    float4 v = xp[q];
    xr[q * 4 + 0] = v.x; xr[q * 4 + 1] = v.y; xr[q * 4 + 2] = v.z; xr[q * 4 + 3] = v.w;
  }
  float acc[OUT_F];
#pragma unroll
  for (int o = 0; o < OUT_F; ++o) acc[o] = bl[o];
#pragma unroll
  for (int i = 0; i < IN_F; ++i) {
    float xi = xr[i];
#pragma unroll
    for (int o = 0; o < OUT_F; ++o) acc[o] = fmaf(xi, rl[i * OUT_F + o], acc[o]);
  }
  if (valid) {
    float4* op = (float4*)(agg + (size_t)n * OUT_F);
#pragma unroll
    for (int q = 0; q < OUT_F / 4; ++q)
      op[q] = make_float4(acc[q * 4 + 0], acc[q * 4 + 1], acc[q * 4 + 2], acc[q * 4 + 3]);
  }
}

__global__ __launch_bounds__(256) void edge_kernel(
    const float* __restrict__ x, const float* __restrict__ ef,
    const float* __restrict__ W, const float* __restrict__ b,
    const int* __restrict__ ei, float* __restrict__ agg, int E) {
  __shared__ float Wl[EDGE_F * IN_F * OUT_F];
  int e = blockIdx.x * blockDim.x + threadIdx.x;
  bool valid = (e < E);
  int eu = valid ? e : 0;
  int s = ei[eu];
  int d = ei[E + eu];
  float efr[EDGE_F];
  {
    const float4* ep = (const float4*)(ef + (size_t)eu * EDGE_F);
#pragma unroll
    for (int q = 0; q < EDGE_F / 4; ++q) {
      float4 v = ep[q];
      efr[q * 4 + 0] = v.x; efr[q * 4 + 1] = v.y;
      efr[q * 4 + 2] = v.z; efr[q * 4 + 3] = v.w;
    }
  }
  const float* xrow = x + (size_t)s * IN_F;
  float acc[OUT_F];
#pragma unroll
  for (int o = 0; o < OUT_F; ++o) acc[o] = 0.f;
  for (int t = threadIdx.x; t < IN_F * OUT_F; t += 256) Wl[t] = b[t];
  __syncthreads();
  for (int i = 0; i < IN_F; ++i) {
    float xi = xrow[i];
    const float* br = &Wl[i * OUT_F];
#pragma unroll
    for (int o = 0; o < OUT_F; ++o) acc[o] = fmaf(xi, br[o], acc[o]);
  }
  __syncthreads();
  for (int t = threadIdx.x; t < EDGE_F * IN_F * OUT_F / 4; t += 256)
    ((float4*)Wl)[t] = ((const float4*)W)[t];
  __syncthreads();
  for (int i = 0; i < IN_F; ++i) {
    float xi = xrow[i];
#pragma unroll
    for (int f = 0; f < EDGE_F; ++f) {
      float m = efr[f] * xi;
      const float* wr = &Wl[(f * IN_F + i) * OUT_F];
#pragma unroll
      for (int o = 0; o < OUT_F; ++o) acc[o] = fmaf(m, wr[o], acc[o]);
    }
  }
  if (valid) {
    float* dp = agg + (size_t)d * OUT_F;
#pragma unroll
    for (int o = 0; o < OUT_F; ++o) atomicAdd(dp + o, acc[o]);
  }
}

// ---------------- K3: BN stats ----------------
__global__ __launch_bounds__(256) void bn_stats_kernel(
    const float* __restrict__ h, float* __restrict__ stats, int total) {
  int t = blockIdx.x * blockDim.x + threadIdx.x;
  int stride = gridDim.x * blockDim.x;
  float s = 0.f, s2 = 0.f;
  for (int idx = t; idx < total; idx += stride) {
    float v = h[idx];
    s += v;
    s2 = fmaf(v, v, s2);
  }
  __shared__ float ls[256], ls2[256];
  ls[threadIdx.x] = s;
  ls2[threadIdx.x] = s2;
  __syncthreads();
  if (threadIdx.x < 32) {
    float a = ls[threadIdx.x], a2 = ls2[threadIdx.x];
    for (int j = 32 + threadIdx.x; j < 256; j += 32) { a += ls[j]; a2 += ls2[j]; }
    atomicAdd(&stats[threadIdx.x], a);
    atomicAdd(&stats[32 + threadIdx.x], a2);
  }
}

// ---------------- K4: normalize + affine + LeakyReLU ----------------
__global__ __launch_bounds__(256) void bn_apply_kernel(
    float* __restrict__ h, const float* __restrict__ stats,
    const float* __restrict__ gamma, const float* __restrict__ beta,
    int total, float invN) {
  int t = blockIdx.x * blockDim.x + threadIdx.x;
  int i4 = t * 4;
  if (i4 >= total) return;
  float4 v = *(const float4*)(h + i4);
  float r[4] = {v.x, v.y, v.z, v.w};
  int o0 = i4 & 31;
#pragma unroll
  for (int j = 0; j < 4; ++j) {
    int o = o0 + j;
    float m = stats[o] * invN;
    float var = fmaf(-m, m, stats[32 + o] * invN);
    float sc = rsqrtf(var + BN_EPS) * gamma[o];
    float val = (r[j] - m) * sc + beta[o];
    r[j] = val >= 0.f ? val : SLOPE * val;
  }
  *(float4*)(h + i4) = make_float4(r[0], r[1], r[2], r[3]);
}

extern "C" void kernel_launch(void* const* d_in, const int* in_sizes, int n_in,
                              void* d_out, int out_size, void* d_ws, size_t ws_size,
                              hipStream_t stream) {
  const float* x     = (const float*)d_in[0];
  const float* ef    = (const float*)d_in[1];
  const float* W     = (const float*)d_in[2];
  const float* b     = (const float*)d_in[3];
  const float* root  = (const float*)d_in[4];
  const float* bias  = (const float*)d_in[5];
  const float* gamma = (const float*)d_in[6];
  const float* beta  = (const float*)d_in[7];
  const int*   ei    = (const int*)d_in[8];

  float* out = (float*)d_out;
  float* stats = (float*)d_ws;                        // 64 floats @ 0
  half_t* BtG = (half_t*)((char*)d_ws + 1024);        // 576*32 fp16 = 36864 B
  half_t* Y = (half_t*)((char*)d_ws + 1024 + 36864);  // [N][17][32] fp16

  int N = in_sizes[0] / IN_F;
  int E = in_sizes[1] / EDGE_F;
  int total = N * OUT_F;
  size_t need = 1024 + 36864 + (size_t)N * 544 * sizeof(half_t);

  hipMemsetAsync(stats, 0, 64 * sizeof(float), stream);

  if (ws_size >= need) {
    prep_bt_kernel<<<(BCOLS * 32 + 255) / 256, 256, 0, stream>>>(W, b, root, BtG);
    gemm_y_mfma_kernel<<<(N + 63) / 64, 256, 0, stream>>>(x, BtG, bias, Y, out, N);
    edge_light_kernel<<<(E + 31) / 32, 256, 0, stream>>>(Y, ef, ei, out, E);
  } else {
    node_root_kernel<<<(N + 255) / 256, 256, 0, stream>>>(x, root, bias, out, N);
    edge_kernel<<<(E + 255) / 256, 256, 0, stream>>>(x, ef, W, b, ei, out, E);
  }
  bn_stats_kernel<<<1024, 256, 0, stream>>>(out, stats, total);
  bn_apply_kernel<<<(total / 4 + 255) / 256, 256, 0, stream>>>(out, stats, gamma, beta, total, 1.0f / (float)N);
}